// Round 18
// baseline (176.594 us; speedup 1.0000x reference)
//
#include <hip/hip_runtime.h>

#define BB 2
#define TT 2048
#define DD 1024
#define HH 16
#define DHD 64
#define MM (BB*TT)   // 4096

typedef __attribute__((ext_vector_type(8))) short short8;
typedef __attribute__((ext_vector_type(4))) float float4v;
typedef unsigned short u16;

__device__ inline float bf2f(u16 u) {
    union { unsigned int i; float f; } v;
    v.i = ((unsigned int)u) << 16;
    return v.f;
}
__device__ inline u16 f2bf(float f) {
    union { float f; unsigned int i; } v;
    v.f = f;
    unsigned int x = v.i;
    unsigned int r = (x + 0x7fffu + ((x >> 16) & 1u)) >> 16;
    return (u16)r;
}

// ---------------- prep: fused x-cast (z==4) + weight cast/transpose (z<4) ----------------
__global__ __launch_bounds__(256) void prep_k(const float* __restrict__ x,
                                              const float* __restrict__ Wq,
                                              const float* __restrict__ Wk,
                                              const float* __restrict__ Wv,
                                              const float* __restrict__ Wo,
                                              u16* __restrict__ xb,
                                              u16* __restrict__ WT) {
    int tid = threadIdx.x;
    if (blockIdx.z == 4) {   // cast x: 1024 blocks x 1024 float4
        int bid = blockIdx.y * 32 + blockIdx.x;
#pragma unroll
        for (int k = 0; k < 4; k++) {
            int i = bid * 1024 + k * 256 + tid;
            float4v v = ((const float4v*)x)[i];
            ushort4 o;
            o.x = f2bf(v[0]); o.y = f2bf(v[1]); o.z = f2bf(v[2]); o.w = f2bf(v[3]);
            ((ushort4*)xb)[i] = o;
        }
        return;
    }
    __shared__ u16 t[32][33];
    int wsel = blockIdx.z;
    const float* W = (wsel == 0) ? Wq : (wsel == 1) ? Wk : (wsel == 2) ? Wv : Wo;
    u16* o = WT + (size_t)wsel * DD * DD;
    int k0 = blockIdx.y * 32, n0 = blockIdx.x * 32;
    int tx = tid & 31, ty = tid >> 5;   // 32 x 8
#pragma unroll
    for (int i = 0; i < 4; i++) {
        int k = ty + i * 8;
        t[k][tx] = f2bf(W[(size_t)(k0 + k) * DD + n0 + tx]);
    }
    __syncthreads();
#pragma unroll
    for (int i = 0; i < 4; i++) {
        int n = ty + i * 8;
        o[(size_t)(n0 + n) * DD + k0 + tx] = t[tx][n];
    }
}

// ---------------- GEMM: BK-parameterized, XOR-swizzled, reg-prefetch (r11 skeleton) --------
// Critical path scales with NK = K/BK barrier rounds (r9-r11). BK=128 halves
// rounds. Swizzle: global chunk c of row r stored at LDS chunk c^(r&7) (flips
// low 3 bits only) -> b128 reads/writes stay 2-way-free for BK in {64,128}.
template <int MODE, int TM, int TN, int BK>
__global__ __launch_bounds__(256) void gemm_k(const u16* __restrict__ A,
                                              const u16* __restrict__ WT0,
                                              void* __restrict__ outp) {
    const int K = DD;
    const int MT = TM / 32, NT = TN / 32;
    const int NS = (TM + TN) * (BK / 8) / 256;
    const int CPR = BK / 8;                      // 16B chunks per row

    int z = blockIdx.z;
    const u16* WT = WT0 + (size_t)z * DD * DD;
    int n0 = blockIdx.x * TN, m0 = blockIdx.y * TM;

    __shared__ u16 S[(TM + TN) * BK];

    int tid = threadIdx.x;
    int lane = tid & 63, w = tid >> 6;
    int wm = (w >> 1) * (TM / 2), wn = (w & 1) * (TN / 2);
    int quad = lane >> 4, l16 = lane & 15;

    const u16* gp[NS];
    u16* lp[NS];
#pragma unroll
    for (int j = 0; j < NS; j++) {
        int cid = tid + j * 256;
        int r = cid / CPR, c = cid % CPR;
        lp[j] = S + r * BK + (c ^ (r & 7)) * 8;
        gp[j] = (r < TM ? A + (size_t)(m0 + r) * K
                        : WT + (size_t)(n0 + r - TM) * K) + c * 8;
    }
    int swz = l16 & 7;

    float4v acc[MT][NT];
#pragma unroll
    for (int i = 0; i < MT; i++)
#pragma unroll
        for (int j = 0; j < NT; j++) acc[i][j] = (float4v)(0.0f);

    short8 pr[NS];
#pragma unroll
    for (int j = 0; j < NS; j++) pr[j] = *(const short8*)gp[j];

    const int NK = K / BK;
#pragma unroll 1
    for (int ki = 0; ki < NK; ki++) {
        __syncthreads();
#pragma unroll
        for (int j = 0; j < NS; j++) *(short8*)lp[j] = pr[j];
        __syncthreads();

        if (ki + 1 < NK) {
            int k0 = (ki + 1) * BK;
#pragma unroll
            for (int j = 0; j < NS; j++) pr[j] = *(const short8*)(gp[j] + k0);
        }

#pragma unroll
        for (int ks = 0; ks < BK / 32; ks++) {
            int cq = ((ks * 4 + quad) ^ swz) * 8;
            short8 a[MT], b[NT];
#pragma unroll
            for (int mt = 0; mt < MT; mt++)
                a[mt] = *(const short8*)&S[(wm + mt * 16 + l16) * BK + cq];
#pragma unroll
            for (int nt = 0; nt < NT; nt++)
                b[nt] = *(const short8*)&S[(TM + wn + nt * 16 + l16) * BK + cq];
#pragma unroll
            for (int mt = 0; mt < MT; mt++)
#pragma unroll
                for (int nt = 0; nt < NT; nt++)
                    acc[mt][nt] = __builtin_amdgcn_mfma_f32_16x16x32_bf16(
                        a[mt], b[nt], acc[mt][nt], 0, 0, 0);
        }
    }

#pragma unroll
    for (int mt = 0; mt < MT; mt++) {
#pragma unroll
        for (int nt = 0; nt < NT; nt++) {
#pragma unroll
            for (int r = 0; r < 4; r++) {
                int m = m0 + wm + mt * 16 + quad * 4 + r;
                int n = n0 + wn + nt * 16 + l16;
                float v = acc[mt][nt][r];
                if constexpr (MODE == 0) {
                    int bb = m >> 11, t = m & 2047;
                    int h = n >> 6, dh = n & 63;
                    size_t idx;
                    if (z == 2)   // V stored transposed: (b,h,dh,t)
                        idx = (((size_t)2 * BB * HH + bb * HH + h) * DHD + dh) * TT + t;
                    else
                        idx = (((size_t)z * BB * HH + bb * HH + h) * TT + t) * DHD + dh;
                    ((u16*)outp)[idx] = f2bf(v);
                } else {
                    ((float*)outp)[(size_t)m * DD + n] = v;
                }
            }
        }
    }
}

// ---------------- flash attention: r16 winner, unchanged ----------------
__global__ __launch_bounds__(512) void attn_k(const u16* __restrict__ QKV,
                                              u16* __restrict__ AO) {
    const u16* Q  = QKV;
    const u16* Kp = QKV + (size_t)MM * DD;
    const u16* Vp = QKV + (size_t)2 * MM * DD;   // V^T: per head [DHD][TT]
    int bh = blockIdx.y;
    int tswz = (blockIdx.x + blockIdx.y) & 15;
    int p = (blockIdx.y & 16) ? (15 - tswz) : tswz;
    int qA = p, qB = 31 - p;
    size_t hoff = (size_t)bh * TT * DHD;

    __shared__ u16 Qs[2][64 * 64];
    __shared__ u16 Ks[2][64 * 64];
    __shared__ u16 VTs[2][64 * 64];
    __shared__ u16 Ps[8][16 * 64];

    int tid = threadIdx.x;
    int lane = tid & 63, wv = tid >> 6;      // 8 waves
    int g = wv >> 2, w4 = wv & 3;            // group (phase), 16-row block
    int quad = lane >> 4, l16 = lane & 15;

    // staging: one 16B chunk per thread per 64x64 tile
    int sr = tid >> 3, sc = tid & 7;
    int sl = sr * 64 + ((sc ^ (sr & 7)) * 8);
    const u16* gK = Kp + hoff + (size_t)sr * DHD + sc * 8;
    const u16* gV = Vp + hoff + (size_t)sr * TT + sc * 8;

    // stage both Q tiles, scaled by (1/sqrt(DH)) * log2(e)
    const float qscale = 0.125f * 1.4426950408889634f;
#pragma unroll
    for (int t = 0; t < 2; t++) {
        int q0 = (t ? qB : qA) * 64;
        short8 v = *(const short8*)(Q + hoff + (size_t)(q0 + sr) * DHD + sc * 8);
        short8 sv;
#pragma unroll
        for (int e = 0; e < 8; e++) sv[e] = (short)f2bf(bf2f((u16)v[e]) * qscale);
        *(short8*)&Qs[t][sl] = sv;
    }

    short8 prK = *(const short8*)gK;   // prefetch KV tile 0
    short8 prV = *(const short8*)gV;

    __syncthreads();   // Q staged
    int cxs = l16 & 7;
    int fr = w4 * 16 + l16;   // my q-row within my tile
    short8 aq0 = *(const short8*)&Qs[g][fr * 64 + ((quad ^ cxs) * 8)];
    short8 aq1 = *(const short8*)&Qs[g][fr * 64 + (((4 + quad) ^ cxs) * 8)];

    int myqt = g ? qB : qA;
    int ntile = myqt + 1;     // my compute-active rounds
    int NR = qB + 1;          // total rounds (B's range covers A's)

    float4v o[4];
#pragma unroll
    for (int i = 0; i < 4; i++) o[i] = (float4v)(0.0f);
    float lr = 0.0f;

#pragma unroll 1
    for (int jt = 0; jt < NR; jt++) {
        int db = jt & 1;
        *(short8*)&Ks[db][sl]  = prK;
        *(short8*)&VTs[db][sl] = prV;
        __syncthreads();

        if (jt + 1 < NR) {   // prefetch next KV tile; in flight under compute
            size_t nj = (size_t)(jt + 1) * 64;
            prK = *(const short8*)(gK + nj * DHD);
            prV = *(const short8*)(gV + nj);
        }

        if (jt < ntile) {
            // S^T (64 kv x 16 q per wave) = K·Q^T
            float4v s[4];
#pragma unroll
            for (int ct = 0; ct < 4; ct++) {
                int kr = (ct * 16 + l16) * 64;
                short8 ak0 = *(const short8*)&Ks[db][kr + ((quad ^ cxs) * 8)];
                short8 ak1 = *(const short8*)&Ks[db][kr + (((4 + quad) ^ cxs) * 8)];
                float4v sv = (float4v)(0.0f);
                sv = __builtin_amdgcn_mfma_f32_16x16x32_bf16(ak0, aq0, sv, 0, 0, 0);
                sv = __builtin_amdgcn_mfma_f32_16x16x32_bf16(ak1, aq1, sv, 0, 0, 0);
                s[ct] = sv;   // lane: kv = ct*16+quad*4+r, q = fr
            }

            if (jt == myqt) {   // diagonal tile: mask kv > q (local coords)
                int ql = w4 * 16 + l16;
#pragma unroll
                for (int ct = 0; ct < 4; ct++)
#pragma unroll
                    for (int r = 0; r < 4; r++) {
                        int kvl = ct * 16 + quad * 4 + r;
                        if (kvl > ql) s[ct][r] = -30000.0f;
                    }
            }

            // p = v_exp_f32(s); P write (C->A layout) as swizzled 8B stores
#pragma unroll
            for (int ct = 0; ct < 4; ct++) {
                float p0 = __builtin_amdgcn_exp2f(s[ct][0]);
                float p1 = __builtin_amdgcn_exp2f(s[ct][1]);
                float p2 = __builtin_amdgcn_exp2f(s[ct][2]);
                float p3 = __builtin_amdgcn_exp2f(s[ct][3]);
                lr += (p0 + p1) + (p2 + p3);
                union { float f; unsigned u; } c0, c1, c2, c3;
                c0.f = p0; c1.f = p1; c2.f = p2; c3.f = p3;
                ushort4 pw;
                pw.x = (u16)(c0.u >> 16);
                pw.y = (u16)(c1.u >> 16);
                pw.z = (u16)(c2.u >> 16);
                pw.w = (u16)(c3.u >> 16);
                int chnk = (ct * 2 + (quad >> 1)) ^ cxs;
                *(ushort4*)&Ps[wv][l16 * 64 + chnk * 8 + (quad & 1) * 4] = pw;
            }

            short8 ap0 = *(const short8*)&Ps[wv][l16 * 64 + ((quad ^ cxs) * 8)];
            short8 ap1 = *(const short8*)&Ps[wv][l16 * 64 + (((4 + quad) ^ cxs) * 8)];
#pragma unroll
            for (int ct = 0; ct < 4; ct++) {
                int vr = (ct * 16 + l16) * 64;
                short8 bv0 = *(const short8*)&VTs[db][vr + ((quad ^ cxs) * 8)];
                short8 bv1 = *(const short8*)&VTs[db][vr + (((4 + quad) ^ cxs) * 8)];
                o[ct] = __builtin_amdgcn_mfma_f32_16x16x32_bf16(ap0, bv0, o[ct], 0, 0, 0);
                o[ct] = __builtin_amdgcn_mfma_f32_16x16x32_bf16(ap1, bv1, o[ct], 0, 0, 0);
            }
        }
    }

    // reduce row sums across quads (lane holds q = w4*16 + l16)
    float rs = lr;
    rs += __shfl_xor(rs, 16);
    rs += __shfl_xor(rs, 32);
    int gbase = lane & 48;
    float rinv[4];
#pragma unroll
    for (int r = 0; r < 4; r++)
        rinv[r] = 1.0f / __shfl(rs, gbase + quad * 4 + r);

    int b = bh >> 4, h = bh & 15;
    int q0 = myqt * 64;
#pragma unroll
    for (int ct = 0; ct < 4; ct++) {
#pragma unroll
        for (int r = 0; r < 4; r++) {
            int q = q0 + w4 * 16 + quad * 4 + r;
            int d = h * 64 + ct * 16 + l16;
            AO[(size_t)(b * TT + q) * DD + d] = f2bf(o[ct][r] * rinv[r]);
        }
    }
}

extern "C" void kernel_launch(void* const* d_in, const int* in_sizes, int n_in,
                              void* d_out, int out_size, void* d_ws, size_t ws_size,
                              hipStream_t stream) {
    const float* x  = (const float*)d_in[0];
    const float* Wq = (const float*)d_in[1];
    const float* Wk = (const float*)d_in[2];
    const float* Wv = (const float*)d_in[3];
    const float* Wo = (const float*)d_in[4];

    u16* xb  = (u16*)d_ws;                       // 8 MB  : x in bf16
    u16* WT  = xb + (size_t)MM * DD;             // 8 MB  : 4 transposed weights bf16
    u16* QKV = WT + (size_t)4 * DD * DD;         // 24 MB : Q,K (b,h,t,dh) + V^T (b,h,dh,t)
    u16* AO  = QKV + (size_t)3 * MM * DD;        // 8 MB  : attention out (B,T,D) bf16
    float* out = (float*)d_out;

    prep_k<<<dim3(32, 32, 5), 256, 0, stream>>>(x, Wq, Wk, Wv, Wo, xb, WT);
    gemm_k<0, 64, 128, 128><<<dim3(DD / 128, MM / 64, 3), 256, 0, stream>>>(xb, WT, QKV);
    attn_k<<<dim3(16, 32), 512, 0, stream>>>(QKV, AO);
    gemm_k<1, 64, 128, 128><<<dim3(DD / 128, MM / 64, 1), 256, 0, stream>>>(AO, WT + (size_t)3 * DD * DD, out);
}

// Round 19
// 167.015 us; speedup vs baseline: 1.0574x; 1.0574x over previous
//
#include <hip/hip_runtime.h>

#define BB 2
#define TT 2048
#define DD 1024
#define HH 16
#define DHD 64
#define MM (BB*TT)   // 4096

typedef __attribute__((ext_vector_type(8))) short short8;
typedef __attribute__((ext_vector_type(4))) float float4v;
typedef unsigned short u16;

__device__ inline float bf2f(u16 u) {
    union { unsigned int i; float f; } v;
    v.i = ((unsigned int)u) << 16;
    return v.f;
}
__device__ inline u16 f2bf(float f) {
    union { float f; unsigned int i; } v;
    v.f = f;
    unsigned int x = v.i;
    unsigned int r = (x + 0x7fffu + ((x >> 16) & 1u)) >> 16;
    return (u16)r;
}

// ---------------- prep: fused x-cast (z==4) + weight cast/transpose (z<4) ----------------
__global__ __launch_bounds__(256) void prep_k(const float* __restrict__ x,
                                              const float* __restrict__ Wq,
                                              const float* __restrict__ Wk,
                                              const float* __restrict__ Wv,
                                              const float* __restrict__ Wo,
                                              u16* __restrict__ xb,
                                              u16* __restrict__ WT) {
    int tid = threadIdx.x;
    if (blockIdx.z == 4) {   // cast x: 1024 blocks x 1024 float4
        int bid = blockIdx.y * 32 + blockIdx.x;
#pragma unroll
        for (int k = 0; k < 4; k++) {
            int i = bid * 1024 + k * 256 + tid;
            float4v v = ((const float4v*)x)[i];
            ushort4 o;
            o.x = f2bf(v[0]); o.y = f2bf(v[1]); o.z = f2bf(v[2]); o.w = f2bf(v[3]);
            ((ushort4*)xb)[i] = o;
        }
        return;
    }
    __shared__ u16 t[32][33];
    int wsel = blockIdx.z;
    const float* W = (wsel == 0) ? Wq : (wsel == 1) ? Wk : (wsel == 2) ? Wv : Wo;
    u16* o = WT + (size_t)wsel * DD * DD;
    int k0 = blockIdx.y * 32, n0 = blockIdx.x * 32;
    int tx = tid & 31, ty = tid >> 5;   // 32 x 8
#pragma unroll
    for (int i = 0; i < 4; i++) {
        int k = ty + i * 8;
        t[k][tx] = f2bf(W[(size_t)(k0 + k) * DD + n0 + tx]);
    }
    __syncthreads();
#pragma unroll
    for (int i = 0; i < 4; i++) {
        int n = ty + i * 8;
        o[(size_t)(n0 + n) * DD + k0 + tx] = t[tx][n];
    }
}

// ---------------- GEMM (r16 winner, BK=64): XOR-swizzled, reg-prefetch ----------------
template <int MODE, int TM, int TN, int BK>
__global__ __launch_bounds__(256) void gemm_k(const u16* __restrict__ A,
                                              const u16* __restrict__ WT0,
                                              void* __restrict__ outp) {
    const int K = DD;
    const int MT = TM / 32, NT = TN / 32;
    const int NS = (TM + TN) * (BK / 8) / 256;
    const int CPR = BK / 8;

    int z = blockIdx.z;
    const u16* WT = WT0 + (size_t)z * DD * DD;
    int n0 = blockIdx.x * TN, m0 = blockIdx.y * TM;

    __shared__ u16 S[(TM + TN) * BK];

    int tid = threadIdx.x;
    int lane = tid & 63, w = tid >> 6;
    int wm = (w >> 1) * (TM / 2), wn = (w & 1) * (TN / 2);
    int quad = lane >> 4, l16 = lane & 15;

    const u16* gp[NS];
    u16* lp[NS];
#pragma unroll
    for (int j = 0; j < NS; j++) {
        int cid = tid + j * 256;
        int r = cid / CPR, c = cid % CPR;
        lp[j] = S + r * BK + (c ^ (r & 7)) * 8;
        gp[j] = (r < TM ? A + (size_t)(m0 + r) * K
                        : WT + (size_t)(n0 + r - TM) * K) + c * 8;
    }
    int swz = l16 & 7;

    float4v acc[MT][NT];
#pragma unroll
    for (int i = 0; i < MT; i++)
#pragma unroll
        for (int j = 0; j < NT; j++) acc[i][j] = (float4v)(0.0f);

    short8 pr[NS];
#pragma unroll
    for (int j = 0; j < NS; j++) pr[j] = *(const short8*)gp[j];

    const int NK = K / BK;
#pragma unroll 1
    for (int ki = 0; ki < NK; ki++) {
        __syncthreads();
#pragma unroll
        for (int j = 0; j < NS; j++) *(short8*)lp[j] = pr[j];
        __syncthreads();

        if (ki + 1 < NK) {
            int k0 = (ki + 1) * BK;
#pragma unroll
            for (int j = 0; j < NS; j++) pr[j] = *(const short8*)(gp[j] + k0);
        }

#pragma unroll
        for (int ks = 0; ks < BK / 32; ks++) {
            int cq = ((ks * 4 + quad) ^ swz) * 8;
            short8 a[MT], b[NT];
#pragma unroll
            for (int mt = 0; mt < MT; mt++)
                a[mt] = *(const short8*)&S[(wm + mt * 16 + l16) * BK + cq];
#pragma unroll
            for (int nt = 0; nt < NT; nt++)
                b[nt] = *(const short8*)&S[(TM + wn + nt * 16 + l16) * BK + cq];
#pragma unroll
            for (int mt = 0; mt < MT; mt++)
#pragma unroll
                for (int nt = 0; nt < NT; nt++)
                    acc[mt][nt] = __builtin_amdgcn_mfma_f32_16x16x32_bf16(
                        a[mt], b[nt], acc[mt][nt], 0, 0, 0);
        }
    }

#pragma unroll
    for (int mt = 0; mt < MT; mt++) {
#pragma unroll
        for (int nt = 0; nt < NT; nt++) {
#pragma unroll
            for (int r = 0; r < 4; r++) {
                int m = m0 + wm + mt * 16 + quad * 4 + r;
                int n = n0 + wn + nt * 16 + l16;
                float v = acc[mt][nt][r];
                if constexpr (MODE == 0) {
                    int bb = m >> 11, t = m & 2047;
                    int h = n >> 6, dh = n & 63;
                    size_t idx;
                    if (z == 2)   // V stored transposed: (b,h,dh,t)
                        idx = (((size_t)2 * BB * HH + bb * HH + h) * DHD + dh) * TT + t;
                    else
                        idx = (((size_t)z * BB * HH + bb * HH + h) * TT + t) * DHD + dh;
                    ((u16*)outp)[idx] = f2bf(v);
                } else {
                    ((float*)outp)[(size_t)m * DD + n] = v;
                }
            }
        }
    }
}

// ---------------- flash attention: split-KV, one block per (bh, q-tile) ----------------
// Both 4-wave groups compute the SAME q-tile qt; group g owns kv tiles 2j+g.
// Every wave active every round (r16's merged-pair design idled 50% of
// wave-rounds). No-max softmax => O and rowsum partials combine linearly:
// group 1 dumps partials to LDS once at the end, group 0 adds and writes AO.
// Rounds = ceil((qt+1)/2). Grid: bx=bh, qt=31-by -> long blocks dispatch first.
// XOR-swizzled unpadded LDS (0-conflict family), S^T trick, raw v_exp_f32.
__global__ __launch_bounds__(512) void attn_k(const u16* __restrict__ QKV,
                                              u16* __restrict__ AO) {
    const u16* Q  = QKV;
    const u16* Kp = QKV + (size_t)MM * DD;
    const u16* Vp = QKV + (size_t)2 * MM * DD;   // V^T: per head [DHD][TT]
    int bh = blockIdx.x;
    int qt = 31 - blockIdx.y;
    size_t hoff = (size_t)bh * TT * DHD;

    __shared__ u16 Ks[2][2][64 * 64];    // [dbuf][group-tile]
    __shared__ u16 VTs[2][2][64 * 64];
    __shared__ u16 Ps[8][16 * 64];       // per-wave P scratch; Q staged in Ps[0..3]

    int tid = threadIdx.x;
    int lane = tid & 63, wv = tid >> 6;      // 8 waves
    int g = wv >> 2, w4 = wv & 3;            // KV-split group, 16-row q block
    int quad = lane >> 4, l16 = lane & 15;
    int cxs = l16 & 7;

    // staging: one 16B chunk per thread per 64x64 tile
    int sr = tid >> 3, sc = tid & 7;
    int sl = sr * 64 + ((sc ^ (sr & 7)) * 8);
    const u16* gK = Kp + hoff + (size_t)sr * DHD + sc * 8;
    const u16* gV = Vp + hoff + (size_t)sr * TT + sc * 8;

    u16* Qstage = &Ps[0][0];   // 8 KB

    // stage Q tile qt, scaled by (1/sqrt(DH)) * log2(e)
    const float qscale = 0.125f * 1.4426950408889634f;
    int q0 = qt * 64;
    {
        short8 v = *(const short8*)(Q + hoff + (size_t)(q0 + sr) * DHD + sc * 8);
        short8 sv;
#pragma unroll
        for (int e = 0; e < 8; e++) sv[e] = (short)f2bf(bf2f((u16)v[e]) * qscale);
        *(short8*)&Qstage[sl] = sv;
    }

    // prefetch round-0 KV tiles (0 and 1)
    short8 prK[2], prV[2];
    prK[0] = *(const short8*)gK;
    prK[1] = *(const short8*)(gK + (size_t)64 * DHD);
    prV[0] = *(const short8*)gV;
    prV[1] = *(const short8*)(gV + 64);

    __syncthreads();   // Q staged
    int fr = w4 * 16 + l16;   // my q-row (local)
    short8 aq0 = *(const short8*)&Qstage[fr * 64 + ((quad ^ cxs) * 8)];
    short8 aq1 = *(const short8*)&Qstage[fr * 64 + (((4 + quad) ^ cxs) * 8)];

    int NR = (qt >> 1) + 1;   // rounds (2 tiles staged per round)

    float4v o[4];
#pragma unroll
    for (int i = 0; i < 4; i++) o[i] = (float4v)(0.0f);
    float lr = 0.0f;

#pragma unroll 1
    for (int jt = 0; jt < NR; jt++) {
        int db = jt & 1;
#pragma unroll
        for (int tt = 0; tt < 2; tt++) {
            *(short8*)&Ks[db][tt][sl]  = prK[tt];
            *(short8*)&VTs[db][tt][sl] = prV[tt];
        }
        __syncthreads();   // publishes round db; drains Q frag reads on jt==0

        if (jt + 1 < NR) {   // prefetch next round's two tiles
            size_t nj = (size_t)(jt + 1) * 128;
            prK[0] = *(const short8*)(gK + nj * DHD);
            prK[1] = *(const short8*)(gK + (nj + 64) * DHD);
            prV[0] = *(const short8*)(gV + nj);
            prV[1] = *(const short8*)(gV + nj + 64);
        }

        int tj = 2 * jt + g;   // my group's tile this round
        if (tj <= qt) {
            // S^T (64 kv x 16 q per wave) = K·Q^T
            float4v s[4];
#pragma unroll
            for (int ct = 0; ct < 4; ct++) {
                int kr = (ct * 16 + l16) * 64;
                short8 ak0 = *(const short8*)&Ks[db][g][kr + ((quad ^ cxs) * 8)];
                short8 ak1 = *(const short8*)&Ks[db][g][kr + (((4 + quad) ^ cxs) * 8)];
                float4v sv = (float4v)(0.0f);
                sv = __builtin_amdgcn_mfma_f32_16x16x32_bf16(ak0, aq0, sv, 0, 0, 0);
                sv = __builtin_amdgcn_mfma_f32_16x16x32_bf16(ak1, aq1, sv, 0, 0, 0);
                s[ct] = sv;   // lane: kv = ct*16+quad*4+r, q = fr
            }

            if (tj == qt) {   // diagonal tile: mask kv > q (local coords)
                int ql = w4 * 16 + l16;
#pragma unroll
                for (int ct = 0; ct < 4; ct++)
#pragma unroll
                    for (int r = 0; r < 4; r++) {
                        int kvl = ct * 16 + quad * 4 + r;
                        if (kvl > ql) s[ct][r] = -30000.0f;
                    }
            }

            // p = v_exp_f32(s); P write (C->A layout) swizzled 8B stores
#pragma unroll
            for (int ct = 0; ct < 4; ct++) {
                float p0 = __builtin_amdgcn_exp2f(s[ct][0]);
                float p1 = __builtin_amdgcn_exp2f(s[ct][1]);
                float p2 = __builtin_amdgcn_exp2f(s[ct][2]);
                float p3 = __builtin_amdgcn_exp2f(s[ct][3]);
                lr += (p0 + p1) + (p2 + p3);
                union { float f; unsigned u; } c0, c1, c2, c3;
                c0.f = p0; c1.f = p1; c2.f = p2; c3.f = p3;
                ushort4 pw;
                pw.x = (u16)(c0.u >> 16);
                pw.y = (u16)(c1.u >> 16);
                pw.z = (u16)(c2.u >> 16);
                pw.w = (u16)(c3.u >> 16);
                int chnk = (ct * 2 + (quad >> 1)) ^ cxs;
                *(ushort4*)&Ps[wv][l16 * 64 + chnk * 8 + (quad & 1) * 4] = pw;
            }

            short8 ap0 = *(const short8*)&Ps[wv][l16 * 64 + ((quad ^ cxs) * 8)];
            short8 ap1 = *(const short8*)&Ps[wv][l16 * 64 + (((4 + quad) ^ cxs) * 8)];
#pragma unroll
            for (int ct = 0; ct < 4; ct++) {
                int vr = (ct * 16 + l16) * 64;
                short8 bv0 = *(const short8*)&VTs[db][g][vr + ((quad ^ cxs) * 8)];
                short8 bv1 = *(const short8*)&VTs[db][g][vr + (((4 + quad) ^ cxs) * 8)];
                o[ct] = __builtin_amdgcn_mfma_f32_16x16x32_bf16(ap0, bv0, o[ct], 0, 0, 0);
                o[ct] = __builtin_amdgcn_mfma_f32_16x16x32_bf16(ap1, bv1, o[ct], 0, 0, 0);
            }
        }
    }

    // combine group partials: group 1 -> LDS, group 0 adds (sums are linear)
    __syncthreads();   // last round's Ks/VTs reads complete before reuse
    float* Of = (float*)&Ks[0][0][0];    // [w4][ct][r][lane] = 16 KB
    float* Lf = (float*)&VTs[0][0][0];   // [w4][lane] = 1 KB
    if (g == 1) {
#pragma unroll
        for (int ct = 0; ct < 4; ct++)
#pragma unroll
            for (int r = 0; r < 4; r++)
                Of[(((w4 * 4 + ct) * 4 + r) * 64) + lane] = o[ct][r];
        Lf[w4 * 64 + lane] = lr;
    }
    __syncthreads();
    if (g == 0) {
#pragma unroll
        for (int ct = 0; ct < 4; ct++)
#pragma unroll
            for (int r = 0; r < 4; r++)
                o[ct][r] += Of[(((w4 * 4 + ct) * 4 + r) * 64) + lane];
        lr += Lf[w4 * 64 + lane];

        // reduce row sums across quads (lane holds q = w4*16 + l16)
        float rs = lr;
        rs += __shfl_xor(rs, 16);
        rs += __shfl_xor(rs, 32);
        int gbase = lane & 48;
        float rinv[4];
#pragma unroll
        for (int r = 0; r < 4; r++)
            rinv[r] = 1.0f / __shfl(rs, gbase + quad * 4 + r);

        int b = bh >> 4, h = bh & 15;
#pragma unroll
        for (int ct = 0; ct < 4; ct++) {
#pragma unroll
            for (int r = 0; r < 4; r++) {
                int q = q0 + w4 * 16 + quad * 4 + r;
                int d = h * 64 + ct * 16 + l16;
                AO[(size_t)(b * TT + q) * DD + d] = f2bf(o[ct][r] * rinv[r]);
            }
        }
    }
}

extern "C" void kernel_launch(void* const* d_in, const int* in_sizes, int n_in,
                              void* d_out, int out_size, void* d_ws, size_t ws_size,
                              hipStream_t stream) {
    const float* x  = (const float*)d_in[0];
    const float* Wq = (const float*)d_in[1];
    const float* Wk = (const float*)d_in[2];
    const float* Wv = (const float*)d_in[3];
    const float* Wo = (const float*)d_in[4];

    u16* xb  = (u16*)d_ws;                       // 8 MB  : x in bf16
    u16* WT  = xb + (size_t)MM * DD;             // 8 MB  : 4 transposed weights bf16
    u16* QKV = WT + (size_t)4 * DD * DD;         // 24 MB : Q,K (b,h,t,dh) + V^T (b,h,dh,t)
    u16* AO  = QKV + (size_t)3 * MM * DD;        // 8 MB  : attention out (B,T,D) bf16
    float* out = (float*)d_out;

    prep_k<<<dim3(32, 32, 5), 256, 0, stream>>>(x, Wq, Wk, Wv, Wo, xb, WT);
    gemm_k<0, 128, 128, 64><<<dim3(DD / 128, MM / 128, 3), 256, 0, stream>>>(xb, WT, QKV);
    attn_k<<<dim3(32, 32), 512, 0, stream>>>(QKV, AO);
    gemm_k<1, 64, 128, 64><<<dim3(DD / 128, MM / 64, 1), 256, 0, stream>>>(AO, WT + (size_t)3 * DD * DD, out);
}